// Round 17
// baseline (340.416 us; speedup 1.0000x reference)
//
#include <hip/hip_runtime.h>
#include <hip/hip_bf16.h>

#define S_LEN 2048
#define HIDDEN 4096
#define NH 32
#define NKV 8
#define HD 128
#define NQKV 6144   // NH*HD + 2*NKV*HD

typedef __bf16 bf16_t;
typedef __bf16 bf16x8 __attribute__((ext_vector_type(8)));
typedef __bf16 bf16x4 __attribute__((ext_vector_type(4)));
typedef float f32x4 __attribute__((ext_vector_type(4)));

typedef __attribute__((address_space(1))) void gvoid;
typedef __attribute__((address_space(3))) void lvoid;

__device__ __forceinline__ void gload_lds16(const void* g, void* l) {
    __builtin_amdgcn_global_load_lds((gvoid*)g, (lvoid*)l, 16, 0, 0);
}

__device__ __forceinline__ float fast_exp2(float x) {
    return __builtin_amdgcn_exp2f(x);   // v_exp_f32 (2^x native)
}

__device__ __forceinline__ unsigned int pack2_bf16(float lo, float hi) {
    bf16_t l = (bf16_t)lo, h = (bf16_t)hi;
    unsigned short lu, hu;
    __builtin_memcpy(&lu, &l, 2);
    __builtin_memcpy(&hu, &h, 2);
    return ((unsigned int)hu << 16) | (unsigned int)lu;
}

// ---------------- cast fp32 -> bf16 (vectorized) ----------------
__global__ void cast_bf16_kernel(const float* __restrict__ in, bf16_t* __restrict__ out, int n4) {
    int stride = gridDim.x * blockDim.x;
    for (int idx = blockIdx.x * blockDim.x + threadIdx.x; idx < n4; idx += stride) {
        float4 v = ((const float4*)in)[idx];
        bf16x4 o;
        o.x = (bf16_t)v.x; o.y = (bf16_t)v.y; o.z = (bf16_t)v.z; o.w = (bf16_t)v.w;
        ((bf16x4*)out)[idx] = o;
    }
}

// ---------------- fast transpose+cast: fp32 in[R][C] (ldin) -> bf16 out[C][R] (ldout) ----------------
__global__ __launch_bounds__(256) void transpose_cast_kernel(const float* __restrict__ in,
                                                             bf16_t* __restrict__ out,
                                                             int ldin, int ldout) {
    __shared__ unsigned int t2[64][34];
    const int c0 = blockIdx.x * 64, r0 = blockIdx.y * 64;
    const int t = threadIdx.x;
    const int tx4 = t & 15, tp = t >> 4;
#pragma unroll
    for (int i = 0; i < 2; ++i) {
        int rp = tp + i * 16;
        const float* p0 = &in[(size_t)(r0 + 2 * rp) * ldin + c0 + tx4 * 4];
        float4 a = *(const float4*)p0;
        float4 b = *(const float4*)(p0 + ldin);
        t2[tx4 * 4 + 0][rp] = pack2_bf16(a.x, b.x);
        t2[tx4 * 4 + 1][rp] = pack2_bf16(a.y, b.y);
        t2[tx4 * 4 + 2][rp] = pack2_bf16(a.z, b.z);
        t2[tx4 * 4 + 3][rp] = pack2_bf16(a.w, b.w);
    }
    __syncthreads();
    const int q = t & 3, cc = t >> 2;
    uint2 v0 = *(const uint2*)&t2[cc][q * 8 + 0];
    uint2 v1 = *(const uint2*)&t2[cc][q * 8 + 2];
    uint2 v2 = *(const uint2*)&t2[cc][q * 8 + 4];
    uint2 v3 = *(const uint2*)&t2[cc][q * 8 + 6];
    bf16_t* o = &out[(size_t)(c0 + cc) * ldout + r0 + q * 16];
    *(uint4*)o = make_uint4(v0.x, v0.y, v1.x, v1.y);
    *(uint4*)(o + 8) = make_uint4(v2.x, v2.y, v3.x, v3.y);
}

// ---------------- fast transpose bf16 -> bf16 (same scheme, bf16x4 loads) ----------------
__global__ __launch_bounds__(256) void transpose_bf16_kernel(const bf16_t* __restrict__ in,
                                                             bf16_t* __restrict__ out,
                                                             int ldin, int ldout) {
    __shared__ unsigned int t2[64][34];
    const int c0 = blockIdx.x * 64, r0 = blockIdx.y * 64;
    const int t = threadIdx.x;
    const int tx4 = t & 15, tp = t >> 4;
#pragma unroll
    for (int i = 0; i < 2; ++i) {
        int rp = tp + i * 16;
        const bf16_t* p0 = &in[(size_t)(r0 + 2 * rp) * ldin + c0 + tx4 * 4];
        bf16x4 a = *(const bf16x4*)p0;
        bf16x4 b = *(const bf16x4*)(p0 + ldin);
#pragma unroll
        for (int k2 = 0; k2 < 4; ++k2) {
            unsigned short lu, hu;
            bf16_t la = a[k2], hb = b[k2];
            __builtin_memcpy(&lu, &la, 2);
            __builtin_memcpy(&hu, &hb, 2);
            t2[tx4 * 4 + k2][rp] = ((unsigned int)hu << 16) | (unsigned int)lu;
        }
    }
    __syncthreads();
    const int q = t & 3, cc = t >> 2;
    uint2 v0 = *(const uint2*)&t2[cc][q * 8 + 0];
    uint2 v1 = *(const uint2*)&t2[cc][q * 8 + 2];
    uint2 v2 = *(const uint2*)&t2[cc][q * 8 + 4];
    uint2 v3 = *(const uint2*)&t2[cc][q * 8 + 6];
    bf16_t* o = &out[(size_t)(c0 + cc) * ldout + r0 + q * 16];
    *(uint4*)o = make_uint4(v0.x, v0.y, v1.x, v1.y);
    *(uint4*)(o + 8) = make_uint4(v2.x, v2.y, v3.x, v3.y);
}

// ---------------- ring-4 unroll-4 counted-vmcnt GEMM: BM=256, per-wave 64x(BN/2) ----------------
// Same tiling/swizzle as round-16 ring2 (4m x 2n waves, per-wave 64x(BN/2)). Changes:
// (1) RING-4 slots, staging 3 chunks ahead: stage(t+3) targets slot (t+3)%4 = the slot
//     consumed at phase t-1, whose readers finished before barrier-t -> race-free.
// (2) K-loop UNROLLED x4 (NT=128 divisible): slot indices compile-time AND each
//     sub-iteration gets its own fragment registers -> breaks the WAR hazard that
//     serialized next-chunk ds_reads behind prev-chunk MFMAs (the round-16 diagnosis:
//     LDS pipe 965cyc + MFMA 930cyc measured fully SERIAL at 2025 cyc/chunk).
// (3) Gate vmcnt(6) = 2 chunks x 3 loads (exact for 3-load waves, 2-stricter for 4-load
//     waves, never drains; ~2 phases of HBM slack).
template<int BN, typename OutT>
__global__ __launch_bounds__(512, 2) void gemm_ring4_kernel(const bf16_t* __restrict__ A,
                                                            const bf16_t* __restrict__ Bt,
                                                            OutT* __restrict__ C,
                                                            int M, int N, int K) {
    constexpr int NF = BN / 32;          // per-wave col frags (6 for 192, 4 for 128)
    __shared__ bf16_t As[4][256 * 32];
    __shared__ bf16_t Bs[4][BN * 32];
    const int tid = threadIdx.x;
    const int lane = tid & 63, w = tid >> 6;
    const int wm = w >> 1, wn = w & 1;
    const int g = lane >> 4, c16 = lane & 15;
    const int srow = lane >> 2;                              // row within a 16-row DMA instr
    const int scg = ((lane & 3) ^ ((lane >> 3) & 3)) * 8;    // pre-swizzled global chunk (elems)
    const int rdc = (g ^ ((c16 >> 1) & 3)) * 8;              // swizzled read chunk (elems)

    // XCD swizzle, bm-fastest
    const int nbm = M / 256;
    const int cpx = gridDim.x >> 3;
    const int bid = blockIdx.x;
    const int swz = (bid & 7) * cpx + (bid >> 3);
    const int bm = swz % nbm, bn = swz / nbm;

    const bf16_t* Ab = A + (size_t)(bm * 256) * K;
    const bf16_t* Bb = Bt + (size_t)bn * BN * K;

    auto stage = [&](int slot, int kt) {
        const bf16_t* Ak = Ab + (size_t)kt * 32;
        const bf16_t* Bk = Bb + (size_t)kt * 32;
#pragma unroll
        for (int j = 0; j < 2; ++j) {    // A: 16 instrs, 2/wave (rows 32w..32w+31)
            int rb = 32 * w + 16 * j;
            gload_lds16(Ak + (size_t)(rb + srow) * K + scg, &As[slot][rb * 32]);
        }
        if constexpr (BN == 192) {       // B: 12 instrs: waves 0-3 x2, waves 4-7 x1
            if (w < 4) {
#pragma unroll
                for (int j = 0; j < 2; ++j) {
                    int rb = 32 * w + 16 * j;
                    gload_lds16(Bk + (size_t)(rb + srow) * K + scg, &Bs[slot][rb * 32]);
                }
            } else {
                int rb = 128 + 16 * (w - 4);
                gload_lds16(Bk + (size_t)(rb + srow) * K + scg, &Bs[slot][rb * 32]);
            }
        } else {                         // BN==128: B 8 instrs, 1/wave
            int rb = 16 * w;
            gload_lds16(Bk + (size_t)(rb + srow) * K + scg, &Bs[slot][rb * 32]);
        }
    };

    f32x4 acc[4][NF];
#pragma unroll
    for (int i = 0; i < 4; ++i)
#pragma unroll
        for (int j = 0; j < NF; ++j)
            acc[i][j] = (f32x4){0.f, 0.f, 0.f, 0.f};

    const int NT = K / 32;               // 128, divisible by 4
    stage(0, 0);
    stage(1, 1);
    stage(2, 2);

    // one chunk: gate, read frags (fresh regs per sub-iter), stage t+3, MFMA
    auto chunk = [&](int slot, int t) {
        asm volatile("s_waitcnt vmcnt(6)" ::: "memory");
        __builtin_amdgcn_s_barrier();
        __builtin_amdgcn_sched_barrier(0);
        __builtin_amdgcn_s_setprio(1);

        bf16x8 af[4], bf[NF];
#pragma unroll
        for (int i = 0; i < 4; ++i) {
            int arow = wm * 64 + i * 16 + c16;
            af[i] = *(const bf16x8*)&As[slot][arow * 32 + rdc];
        }
#pragma unroll
        for (int j = 0; j < NF; ++j) {
            int brow = wn * (BN / 2) + j * 16 + c16;
            bf[j] = *(const bf16x8*)&Bs[slot][brow * 32 + rdc];
        }
        int nk = t + 3;
        if (nk >= NT) nk -= NT;          // wrap-stage: keeps ledger uniform, never read
        stage((slot + 3) & 3, nk);

        // counted lgkmcnt from the compiler; unroll gives fresh regs -> reads of chunk
        // t+1 can issue beneath these MFMAs
#pragma unroll
        for (int i = 0; i < 4; ++i)
#pragma unroll
            for (int j = 0; j < NF; ++j)
                acc[i][j] = __builtin_amdgcn_mfma_f32_16x16x32_bf16(af[i], bf[j], acc[i][j], 0, 0, 0);
        __builtin_amdgcn_s_setprio(0);
    };

    for (int t4 = 0; t4 < NT; t4 += 4) {
        chunk(0, t4 + 0);
        chunk(1, t4 + 1);
        chunk(2, t4 + 2);
        chunk(3, t4 + 3);
    }

#pragma unroll
    for (int mi = 0; mi < 4; ++mi)
#pragma unroll
        for (int ni = 0; ni < NF; ++ni) {
            int col = bn * BN + wn * (BN / 2) + ni * 16 + c16;
#pragma unroll
            for (int r = 0; r < 4; ++r) {
                int row = bm * 256 + wm * 64 + mi * 16 + g * 4 + r;
                C[(size_t)row * N + col] = (OutT)acc[mi][ni][r];
            }
        }
}

// ---------------- RoPE: in bf16 [S][ld] (head block at col h*128) -> out bf16 [H][S][128] ----------------
__global__ void rope_kernel(const bf16_t* __restrict__ in, bf16_t* __restrict__ out,
                            const int* __restrict__ pos, int H, int ld, float scale) {
    int idx = blockIdx.x * blockDim.x + threadIdx.x;
    int total = S_LEN * H * 64;
    if (idx >= total) return;
    int d = idx & 63;
    int h = (idx >> 6) % H;
    int s = idx / (64 * H);
    const bf16_t* base = in + (size_t)s * ld + h * HD;
    float x0 = (float)base[d], x1 = (float)base[d + 64];
    float p = (float)pos[s];
    float invf = fast_exp2(-0.20762050593046935f * (float)d);  // log2(10000)/64
    float f = p * invf;
    float sn, cs;
    __sincosf(f, &sn, &cs);
    float o0 = (x0 * cs - x1 * sn) * scale;
    float o1 = (x1 * cs + x0 * sn) * scale;
    bf16_t* ob = out + ((size_t)h * S_LEN + s) * HD;
    ob[d] = (bf16_t)o0;
    ob[d + 64] = (bf16_t)o1;
}

// ---------------- flash attention v5 (unchanged from round 15) ----------------
#define PLD 68
__global__ __launch_bounds__(512) void attn_kernel(const bf16_t* __restrict__ Q,
                                                   const bf16_t* __restrict__ K,
                                                   const bf16_t* __restrict__ Vt,
                                                   bf16_t* __restrict__ O) {
    __shared__ bf16_t Ks[4][64 * 128];   // [kv row][d], swizzled chunks
    __shared__ bf16_t Vs[4][128 * 64];   // [d][kv], swizzled chunks
    __shared__ bf16_t Pl[8][16 * PLD];
    const int tid = threadIdx.x;
    const int lane = tid & 63, w = tid >> 6;   // w: 0..7
    const int bid = blockIdx.x;
    const int h = bid & 31;
    const int x = bid >> 5;              // 0..7
    const int grp = w >> 2, wi = w & 3;
    const int kv = h >> 2;               // N_REP = 4
    const int quad = lane >> 4, c16 = lane & 15;
    const int c7 = c16 & 7;
    const bf16_t* Qh = Q + (size_t)h * S_LEN * HD;
    const bf16_t* Kh = K + (size_t)kv * S_LEN * HD;
    const bf16_t* Vh = Vt + (size_t)kv * HD * S_LEN;
    bf16_t* P = Pl[w];

    auto stage = [&](int slot, int kb) {
        bf16_t* Kd = Ks[slot];
        bf16_t* Vd = Vs[slot];
#pragma unroll
        for (int j = 0; j < 2; ++j) {
            int i = w * 2 + j;           // 16 instrs across 8 waves
            {   // K: instr covers 4 rows of 256B
                int row = 4 * i + (lane >> 4);
                int sc = (lane & 15) ^ (row & 7);
                gload_lds16(Kh + (size_t)(kb + row) * HD + sc * 8, Kd + i * 512);
            }
            {   // V: instr covers 8 rows of 128B
                int row = 8 * i + (lane >> 3);
                int sc = (lane & 7) ^ ((lane >> 3) & 7);
                gload_lds16(Vh + (size_t)row * S_LEN + kb + sc * 8, Vd + i * 512);
            }
        }
    };

    bf16x8 ones;
#pragma unroll
    for (int j = 0; j < 8; ++j) ones[j] = (bf16_t)1.0f;

    for (int ph = 0; ph < 2; ++ph) {
        const int qt = (ph == 0) ? x : 15 - x;
        const int R = qt + 1;            // rounds for this q-tile
        const int qb = qt * 128 + wi * 32;

        bf16x8 qf[2][4];
#pragma unroll
        for (int rg = 0; rg < 2; ++rg)
#pragma unroll
            for (int c = 0; c < 4; ++c)
                qf[rg][c] = *(const bf16x8*)(Qh + (size_t)(qb + rg * 16 + c16) * HD + c * 32 + quad * 8);

        f32x4 acc_o[2][8];
#pragma unroll
        for (int rg = 0; rg < 2; ++rg)
#pragma unroll
            for (int dt = 0; dt < 8; ++dt) acc_o[rg][dt] = (f32x4){0.f, 0.f, 0.f, 0.f};
        f32x4 acc_l[2] = {(f32x4){0.f, 0.f, 0.f, 0.f}, (f32x4){0.f, 0.f, 0.f, 0.f}};
        float m[2][4];
#pragma unroll
        for (int rg = 0; rg < 2; ++rg)
#pragma unroll
            for (int r = 0; r < 4; ++r) m[rg][r] = -1e30f;

        stage(0, 0);
        stage(1, 64);
        __syncthreads();

        for (int r = 0; r < R; ++r) {
            int jn0 = 2 * r + 2, jn1 = 2 * r + 3;
            if (jn0 < 2 * R) stage(jn0 & 3, jn0 * 64);
            if (jn1 < 2 * R) stage(jn1 & 3, jn1 * 64);

            const int j = 2 * r + grp;   // this group's kv tile
            const int kb = j * 64;
            const bf16_t* Kb = Ks[j & 3];
            const bf16_t* Vb = Vs[j & 3];

            if (kb <= qb + 31) {         // wave-active
                const bool diag = (kb + 63 > qb);

                f32x4 sacc[2][4];
#pragma unroll
                for (int rg = 0; rg < 2; ++rg)
#pragma unroll
                    for (int t = 0; t < 4; ++t) sacc[rg][t] = (f32x4){0.f, 0.f, 0.f, 0.f};
#pragma unroll
                for (int t = 0; t < 4; ++t) {
                    const bf16_t* krow = Kb + (t * 16 + c16) * 128;
#pragma unroll
                    for (int cc = 0; cc < 4; ++cc) {
                        bf16x8 kf = *(const bf16x8*)(krow + (((cc * 4 + quad) ^ c7) * 8));
                        sacc[0][t] = __builtin_amdgcn_mfma_f32_16x16x32_bf16(qf[0][cc], kf, sacc[0][t], 0, 0, 0);
                        sacc[1][t] = __builtin_amdgcn_mfma_f32_16x16x32_bf16(qf[1][cc], kf, sacc[1][t], 0, 0, 0);
                    }
                }
                bf16x8 pf[2][2];
#pragma unroll
                for (int rg = 0; rg < 2; ++rg) {
                    float p[4][4], mxr[4];
#pragma unroll
                    for (int r4 = 0; r4 < 4; ++r4) {
                        int qq = qb + rg * 16 + quad * 4 + r4;
#pragma unroll
                        for (int t = 0; t < 4; ++t) {
                            float sv = sacc[rg][t][r4];
                            if (diag && (kb + t * 16 + c16 > qq)) sv = -1e30f;
                            p[t][r4] = sv;
                        }
                        float mx = fmaxf(fmaxf(p[0][r4], p[1][r4]), fmaxf(p[2][r4], p[3][r4]));
                        mx = fmaxf(mx, __shfl_xor(mx, 1));
                        mx = fmaxf(mx, __shfl_xor(mx, 2));
                        mx = fmaxf(mx, __shfl_xor(mx, 4));
                        mx = fmaxf(mx, __shfl_xor(mx, 8));
                        mxr[r4] = mx;
                    }
                    bool resc = false;
#pragma unroll
                    for (int r4 = 0; r4 < 4; ++r4) resc = resc || (mxr[r4] > m[rg][r4] + 8.f);
                    if (__any(resc)) {
#pragma unroll
                        for (int r4 = 0; r4 < 4; ++r4) {
                            float mn = fmaxf(m[rg][r4], mxr[r4]);
                            float al = fast_exp2(m[rg][r4] - mn);
                            m[rg][r4] = mn;
                            acc_l[rg][r4] *= al;
#pragma unroll
                            for (int dt = 0; dt < 8; ++dt) acc_o[rg][dt][r4] *= al;
                        }
                    }
#pragma unroll
                    for (int r4 = 0; r4 < 4; ++r4)
#pragma unroll
                        for (int t = 0; t < 4; ++t)
                            p[t][r4] = fast_exp2(p[t][r4] - m[rg][r4]);
#pragma unroll
                    for (int t = 0; t < 4; ++t)
#pragma unroll
                        for (int r4 = 0; r4 < 4; ++r4)
                            P[(quad * 4 + r4) * PLD + t * 16 + c16] = (bf16_t)p[t][r4];
                    pf[rg][0] = *(const bf16x8*)(P + c16 * PLD + quad * 8);
                    pf[rg][1] = *(const bf16x8*)(P + c16 * PLD + 32 + quad * 8);
                }
                acc_l[0] = __builtin_amdgcn_mfma_f32_16x16x32_bf16(pf[0][0], ones, acc_l[0], 0, 0, 0);
                acc_l[0] = __builtin_amdgcn_mfma_f32_16x16x32_bf16(pf[0][1], ones, acc_l[0], 0, 0, 0);
                acc_l[1] = __builtin_amdgcn_mfma_f32_16x16x32_bf16(pf[1][0], ones, acc_l[1], 0, 0, 0);
                acc_l[1] = __builtin_amdgcn_mfma_f32_16x16x32_bf16(pf[1][1], ones, acc_l[1], 0, 0, 0);
#pragma unroll
                for (int dt = 0; dt < 8; ++dt) {
                    const bf16_t* vrow = Vb + (dt * 16 + c16) * 64;
                    bf16x8 vf0 = *(const bf16x8*)(vrow + ((quad ^ c7) * 8));
                    bf16x8 vf1 = *(const bf16x8*)(vrow + (((4 + quad) ^ c7) * 8));
                    acc_o[0][dt] = __builtin_amdgcn_mfma_f32_16x16x32_bf16(pf[0][0], vf0, acc_o[0][dt], 0, 0, 0);
                    acc_o[0][dt] = __builtin_amdgcn_mfma_f32_16x16x32_bf16(pf[0][1], vf1, acc_o[0][dt], 0, 0, 0);
                    acc_o[1][dt] = __builtin_amdgcn_mfma_f32_16x16x32_bf16(pf[1][0], vf0, acc_o[1][dt], 0, 0, 0);
                    acc_o[1][dt] = __builtin_amdgcn_mfma_f32_16x16x32_bf16(pf[1][1], vf1, acc_o[1][dt], 0, 0, 0);
                }
            }
            __syncthreads();
        }

        // ---- merge the two kv-split groups (grp1 -> LDS, grp0 combines & writes O) ----
        float* s0 = (float*)&Ks[0][0];   // 48 idx x 256 x 4B = 49KB <= 64KB
        float* s1 = (float*)&Vs[0][0];   // 32 idx x 256 x 4B = 32KB <= 64KB
        const int sl = wi * 64 + lane;
        if (grp == 1) {
#pragma unroll
            for (int rg = 0; rg < 2; ++rg)
#pragma unroll
                for (int r4 = 0; r4 < 4; ++r4) {
                    s0[(rg * 4 + r4) * 256 + sl] = m[rg][r4];
                    s0[(8 + rg * 4 + r4) * 256 + sl] = acc_l[rg][r4];
                }
#pragma unroll
            for (int dt = 0; dt < 8; ++dt)
#pragma unroll
                for (int r4 = 0; r4 < 4; ++r4) {
                    s0[(16 + dt * 4 + r4) * 256 + sl] = acc_o[0][dt][r4];
                    s1[(dt * 4 + r4) * 256 + sl] = acc_o[1][dt][r4];
                }
        }
        __syncthreads();
        if (grp == 0) {
#pragma unroll
            for (int rg = 0; rg < 2; ++rg)
#pragma unroll
                for (int r4 = 0; r4 < 4; ++r4) {
                    float m1 = s0[(rg * 4 + r4) * 256 + sl];
                    float l1 = s0[(8 + rg * 4 + r4) * 256 + sl];
                    float mm = fmaxf(m[rg][r4], m1);
                    float a0 = fast_exp2(m[rg][r4] - mm);
                    float a1 = fast_exp2(m1 - mm);
                    float ll = acc_l[rg][r4] * a0 + l1 * a1;
                    float inv = 1.f / ll;
                    bf16_t* orow = &O[(size_t)(qb + rg * 16 + quad * 4 + r4) * HIDDEN + h * HD];
#pragma unroll
                    for (int dt = 0; dt < 8; ++dt) {
                        float o1 = (rg == 0) ? s0[(16 + dt * 4 + r4) * 256 + sl]
                                             : s1[(dt * 4 + r4) * 256 + sl];
                        float val = (acc_o[rg][dt][r4] * a0 + o1 * a1) * inv;
                        orow[dt * 16 + c16] = (bf16_t)val;
                    }
                }
        }
        __syncthreads();                 // scratch free before next q-tile's staging
    }
}

// ---------------- host ----------------
extern "C" void kernel_launch(void* const* d_in, const int* in_sizes, int n_in,
                              void* d_out, int out_size, void* d_ws, size_t ws_size,
                              hipStream_t stream) {
    const float* hs = (const float*)d_in[0];
    const float* Wq = (const float*)d_in[1];
    const float* Wk = (const float*)d_in[2];
    const float* Wv = (const float*)d_in[3];
    const float* Wo = (const float*)d_in[4];
    const int* pos = (const int*)d_in[6];
    float* out = (float*)d_out;

    char* ws = (char*)d_ws;
    size_t off = 0;
    auto alloc = [&](size_t bytes) -> void* {
        void* p = ws + off;
        off += (bytes + 255) & ~(size_t)255;
        return p;
    };
    bf16_t* hB    = (bf16_t*)alloc((size_t)S_LEN * HIDDEN * 2);
    bf16_t* WqkvT = (bf16_t*)alloc((size_t)NQKV * HIDDEN * 2);   // [6144][4096]
    bf16_t* WoT   = (bf16_t*)alloc((size_t)HIDDEN * HIDDEN * 2);
    bf16_t* QKV   = (bf16_t*)alloc((size_t)S_LEN * NQKV * 2);    // [2048][6144] bf16
    bf16_t* Qr    = (bf16_t*)alloc((size_t)NH * S_LEN * HD * 2);
    bf16_t* Kr    = (bf16_t*)alloc((size_t)NKV * S_LEN * HD * 2);
    bf16_t* Vt    = (bf16_t*)alloc((size_t)NKV * HD * S_LEN * 2);
    bf16_t* Oat   = (bf16_t*)alloc((size_t)S_LEN * HIDDEN * 2);

    // 1. cast hidden to bf16
    cast_bf16_kernel<<<2048, 256, 0, stream>>>(hs, hB, S_LEN * HIDDEN / 4);
    // 2. transpose-cast weights into fused [6144][4096] (64x64 tiles, vectorized)
    transpose_cast_kernel<<<dim3(HIDDEN / 64, HIDDEN / 64), 256, 0, stream>>>(Wq, WqkvT, HIDDEN, HIDDEN);
    transpose_cast_kernel<<<dim3(1024 / 64, HIDDEN / 64), 256, 0, stream>>>(Wk, WqkvT + (size_t)4096 * HIDDEN, 1024, HIDDEN);
    transpose_cast_kernel<<<dim3(1024 / 64, HIDDEN / 64), 256, 0, stream>>>(Wv, WqkvT + (size_t)5120 * HIDDEN, 1024, HIDDEN);
    transpose_cast_kernel<<<dim3(HIDDEN / 64, HIDDEN / 64), 256, 0, stream>>>(Wo, WoT, HIDDEN, HIDDEN);
    // 3. fused QKV projection -> bf16 [2048][6144]; 256x192 tile -> 256 blocks = 1/CU
    gemm_ring4_kernel<192, bf16_t><<<(S_LEN / 256) * (NQKV / 192), 512, 0, stream>>>(hB, WqkvT, QKV, S_LEN, NQKV, HIDDEN);
    // 4. RoPE; Q scale = log2(e)/sqrt(128) for exp2-domain softmax
    rope_kernel<<<(S_LEN * NH * 64 + 255) / 256, 256, 0, stream>>>(QKV, Qr, pos, NH, NQKV, 0.1275174310f);
    rope_kernel<<<(S_LEN * NKV * 64 + 255) / 256, 256, 0, stream>>>(QKV + 4096, Kr, pos, NKV, NQKV, 1.0f);
    // 5. V transpose: bf16 [S][1024] (stride 6144) -> [1024][2048] == [NKV][128][S]
    transpose_bf16_kernel<<<dim3(1024 / 64, S_LEN / 64), 256, 0, stream>>>(QKV + 5120, Vt, NQKV, S_LEN);
    // 6. flash attention v5: 256 blocks, 1/CU, 17 uniform rounds
    attn_kernel<<<256, 512, 0, stream>>>(Qr, Kr, Vt, Oat);
    // 7. output projection (fp32 out); 256x128 tile -> 256 blocks = 1/CU
    gemm_ring4_kernel<128, float><<<(S_LEN / 256) * (HIDDEN / 128), 512, 0, stream>>>(Oat, WoT, out, S_LEN, HIDDEN, HIDDEN);
}

// Round 18
// 321.313 us; speedup vs baseline: 1.0595x; 1.0595x over previous
//
#include <hip/hip_runtime.h>
#include <hip/hip_bf16.h>

#define S_LEN 2048
#define HIDDEN 4096
#define NH 32
#define NKV 8
#define HD 128
#define NQKV 6144   // NH*HD + 2*NKV*HD

typedef __bf16 bf16_t;
typedef __bf16 bf16x8 __attribute__((ext_vector_type(8)));
typedef __bf16 bf16x4 __attribute__((ext_vector_type(4)));
typedef float f32x4 __attribute__((ext_vector_type(4)));

typedef __attribute__((address_space(1))) void gvoid;
typedef __attribute__((address_space(3))) void lvoid;

__device__ __forceinline__ void gload_lds16(const void* g, void* l) {
    __builtin_amdgcn_global_load_lds((gvoid*)g, (lvoid*)l, 16, 0, 0);
}

__device__ __forceinline__ float fast_exp2(float x) {
    return __builtin_amdgcn_exp2f(x);   // v_exp_f32 (2^x native)
}

__device__ __forceinline__ unsigned int pack2_bf16(float lo, float hi) {
    bf16_t l = (bf16_t)lo, h = (bf16_t)hi;
    unsigned short lu, hu;
    __builtin_memcpy(&lu, &l, 2);
    __builtin_memcpy(&hu, &h, 2);
    return ((unsigned int)hu << 16) | (unsigned int)lu;
}

// ---------------- cast fp32 -> bf16 (vectorized) ----------------
__global__ void cast_bf16_kernel(const float* __restrict__ in, bf16_t* __restrict__ out, int n4) {
    int stride = gridDim.x * blockDim.x;
    for (int idx = blockIdx.x * blockDim.x + threadIdx.x; idx < n4; idx += stride) {
        float4 v = ((const float4*)in)[idx];
        bf16x4 o;
        o.x = (bf16_t)v.x; o.y = (bf16_t)v.y; o.z = (bf16_t)v.z; o.w = (bf16_t)v.w;
        ((bf16x4*)out)[idx] = o;
    }
}

// ---------------- fused weight prep: 4 transpose-casts in ONE launch ----------------
// Wq [4096][4096] -> WqkvT rows 0..4095        (4096 tiles)
// Wk [4096][1024] -> WqkvT rows 4096..5119     (1024 tiles)
// Wv [4096][1024] -> WqkvT rows 5120..6143     (1024 tiles)
// Wo [4096][4096] -> WoT                        (4096 tiles)
// 64x64 tile each; block decodes (matrix, cx, ry) from linear blockIdx.x.
__global__ __launch_bounds__(256) void weight_prep_kernel(const float* __restrict__ Wq,
                                                          const float* __restrict__ Wk,
                                                          const float* __restrict__ Wv,
                                                          const float* __restrict__ Wo,
                                                          bf16_t* __restrict__ WqkvT,
                                                          bf16_t* __restrict__ WoT) {
    __shared__ unsigned int t2[64][34];
    int b = blockIdx.x;
    const float* in;
    bf16_t* out;
    int ldin, ldout, cx, ry;
    if (b < 4096) {               // Wq: 64x64 tiles of [4096r][4096c]
        in = Wq; out = WqkvT; ldin = HIDDEN; ldout = HIDDEN;
        cx = b & 63; ry = b >> 6;
    } else if (b < 5120) {        // Wk
        b -= 4096;
        in = Wk; out = WqkvT + (size_t)4096 * HIDDEN; ldin = 1024; ldout = HIDDEN;
        cx = b & 15; ry = b >> 4;
    } else if (b < 6144) {        // Wv
        b -= 5120;
        in = Wv; out = WqkvT + (size_t)5120 * HIDDEN; ldin = 1024; ldout = HIDDEN;
        cx = b & 15; ry = b >> 4;
    } else {                      // Wo
        b -= 6144;
        in = Wo; out = WoT; ldin = HIDDEN; ldout = HIDDEN;
        cx = b & 63; ry = b >> 6;
    }
    const int c0 = cx * 64, r0 = ry * 64;
    const int t = threadIdx.x;
    const int tx4 = t & 15, tp = t >> 4;
#pragma unroll
    for (int i = 0; i < 2; ++i) {
        int rp = tp + i * 16;
        const float* p0 = &in[(size_t)(r0 + 2 * rp) * ldin + c0 + tx4 * 4];
        float4 a = *(const float4*)p0;
        float4 bb = *(const float4*)(p0 + ldin);
        t2[tx4 * 4 + 0][rp] = pack2_bf16(a.x, bb.x);
        t2[tx4 * 4 + 1][rp] = pack2_bf16(a.y, bb.y);
        t2[tx4 * 4 + 2][rp] = pack2_bf16(a.z, bb.z);
        t2[tx4 * 4 + 3][rp] = pack2_bf16(a.w, bb.w);
    }
    __syncthreads();
    const int q = t & 3, cc = t >> 2;
    uint2 v0 = *(const uint2*)&t2[cc][q * 8 + 0];
    uint2 v1 = *(const uint2*)&t2[cc][q * 8 + 2];
    uint2 v2 = *(const uint2*)&t2[cc][q * 8 + 4];
    uint2 v3 = *(const uint2*)&t2[cc][q * 8 + 6];
    bf16_t* o = &out[(size_t)(c0 + cc) * ldout + r0 + q * 16];
    *(uint4*)o = make_uint4(v0.x, v0.y, v1.x, v1.y);
    *(uint4*)(o + 8) = make_uint4(v2.x, v2.y, v3.x, v3.y);
}

// ---------------- fast transpose bf16 -> bf16 (V transpose) ----------------
__global__ __launch_bounds__(256) void transpose_bf16_kernel(const bf16_t* __restrict__ in,
                                                             bf16_t* __restrict__ out,
                                                             int ldin, int ldout) {
    __shared__ unsigned int t2[64][34];
    const int c0 = blockIdx.x * 64, r0 = blockIdx.y * 64;
    const int t = threadIdx.x;
    const int tx4 = t & 15, tp = t >> 4;
#pragma unroll
    for (int i = 0; i < 2; ++i) {
        int rp = tp + i * 16;
        const bf16_t* p0 = &in[(size_t)(r0 + 2 * rp) * ldin + c0 + tx4 * 4];
        bf16x4 a = *(const bf16x4*)p0;
        bf16x4 b = *(const bf16x4*)(p0 + ldin);
#pragma unroll
        for (int k2 = 0; k2 < 4; ++k2) {
            unsigned short lu, hu;
            bf16_t la = a[k2], hb = b[k2];
            __builtin_memcpy(&lu, &la, 2);
            __builtin_memcpy(&hu, &hb, 2);
            t2[tx4 * 4 + k2][rp] = ((unsigned int)hu << 16) | (unsigned int)lu;
        }
    }
    __syncthreads();
    const int q = t & 3, cc = t >> 2;
    uint2 v0 = *(const uint2*)&t2[cc][q * 8 + 0];
    uint2 v1 = *(const uint2*)&t2[cc][q * 8 + 2];
    uint2 v2 = *(const uint2*)&t2[cc][q * 8 + 4];
    uint2 v3 = *(const uint2*)&t2[cc][q * 8 + 6];
    bf16_t* o = &out[(size_t)(c0 + cc) * ldout + r0 + q * 16];
    *(uint4*)o = make_uint4(v0.x, v0.y, v1.x, v1.y);
    *(uint4*)(o + 8) = make_uint4(v2.x, v2.y, v3.x, v3.y);
}

// ---------------- ring-3 counted-vmcnt GEMM: BM=256, per-wave 64x(BN/2) (round-16 best) ----------------
template<int BN, typename OutT>
__global__ __launch_bounds__(512, 2) void gemm_ring2_kernel(const bf16_t* __restrict__ A,
                                                            const bf16_t* __restrict__ Bt,
                                                            OutT* __restrict__ C,
                                                            int M, int N, int K) {
    constexpr int NF = BN / 32;          // per-wave col frags (6 for 192, 4 for 128)
    __shared__ bf16_t As[3][256 * 32];
    __shared__ bf16_t Bs[3][BN * 32];
    const int tid = threadIdx.x;
    const int lane = tid & 63, w = tid >> 6;
    const int wm = w >> 1, wn = w & 1;
    const int g = lane >> 4, c16 = lane & 15;
    const int srow = lane >> 2;                              // row within a 16-row DMA instr
    const int scg = ((lane & 3) ^ ((lane >> 3) & 3)) * 8;    // pre-swizzled global chunk (elems)
    const int rdc = (g ^ ((c16 >> 1) & 3)) * 8;              // swizzled read chunk (elems)

    // XCD swizzle, bm-fastest
    const int nbm = M / 256;
    const int cpx = gridDim.x >> 3;
    const int bid = blockIdx.x;
    const int swz = (bid & 7) * cpx + (bid >> 3);
    const int bm = swz % nbm, bn = swz / nbm;

    const bf16_t* Ab = A + (size_t)(bm * 256) * K;
    const bf16_t* Bb = Bt + (size_t)bn * BN * K;

    auto stage = [&](int slot, int kt) {
        const bf16_t* Ak = Ab + (size_t)kt * 32;
        const bf16_t* Bk = Bb + (size_t)kt * 32;
#pragma unroll
        for (int j = 0; j < 2; ++j) {    // A: 16 instrs, 2/wave (rows 32w..32w+31)
            int rb = 32 * w + 16 * j;
            gload_lds16(Ak + (size_t)(rb + srow) * K + scg, &As[slot][rb * 32]);
        }
        if constexpr (BN == 192) {       // B: 12 instrs: waves 0-3 x2, waves 4-7 x1
            if (w < 4) {
#pragma unroll
                for (int j = 0; j < 2; ++j) {
                    int rb = 32 * w + 16 * j;
                    gload_lds16(Bk + (size_t)(rb + srow) * K + scg, &Bs[slot][rb * 32]);
                }
            } else {
                int rb = 128 + 16 * (w - 4);
                gload_lds16(Bk + (size_t)(rb + srow) * K + scg, &Bs[slot][rb * 32]);
            }
        } else {                         // BN==128: B 8 instrs, 1/wave
            int rb = 16 * w;
            gload_lds16(Bk + (size_t)(rb + srow) * K + scg, &Bs[slot][rb * 32]);
        }
    };

    f32x4 acc[4][NF];
#pragma unroll
    for (int i = 0; i < 4; ++i)
#pragma unroll
        for (int j = 0; j < NF; ++j)
            acc[i][j] = (f32x4){0.f, 0.f, 0.f, 0.f};

    const int NT = K / 32;
    stage(0, 0);
    stage(1, 1);

    int slot = 0, slot2 = 2;             // slot = t%3, slot2 = (t+2)%3
    for (int t = 0; t < NT; ++t) {
        asm volatile("s_waitcnt vmcnt(3)" ::: "memory");
        __builtin_amdgcn_s_barrier();
        __builtin_amdgcn_sched_barrier(0);
        __builtin_amdgcn_s_setprio(1);

        bf16x8 af[4], bf[NF];
#pragma unroll
        for (int i = 0; i < 4; ++i) {
            int arow = wm * 64 + i * 16 + c16;
            af[i] = *(const bf16x8*)&As[slot][arow * 32 + rdc];
        }
#pragma unroll
        for (int j = 0; j < NF; ++j) {
            int brow = wn * (BN / 2) + j * 16 + c16;
            bf[j] = *(const bf16x8*)&Bs[slot][brow * 32 + rdc];
        }
        int nk = t + 2;
        if (nk >= NT) nk -= NT;          // wrap-stage: keeps ledger uniform, never read
        stage(slot2, nk);

        // NO lgkmcnt(0) fence: compiler interleaves ds_reads with MFMAs (counted lgkmcnt)
#pragma unroll
        for (int i = 0; i < 4; ++i)
#pragma unroll
            for (int j = 0; j < NF; ++j)
                acc[i][j] = __builtin_amdgcn_mfma_f32_16x16x32_bf16(af[i], bf[j], acc[i][j], 0, 0, 0);
        __builtin_amdgcn_s_setprio(0);

        slot = (slot + 1) % 3;
        slot2 = (slot2 + 1) % 3;
    }

#pragma unroll
    for (int mi = 0; mi < 4; ++mi)
#pragma unroll
        for (int ni = 0; ni < NF; ++ni) {
            int col = bn * BN + wn * (BN / 2) + ni * 16 + c16;
#pragma unroll
            for (int r = 0; r < 4; ++r) {
                int row = bm * 256 + wm * 64 + mi * 16 + g * 4 + r;
                C[(size_t)row * N + col] = (OutT)acc[mi][ni][r];
            }
        }
}

// ---------------- fused RoPE (Q and K in one launch): in bf16 [S][NQKV] ----------------
// h < 32: Q head h (cols h*128), out Qr + h*S*HD, scale = log2e/sqrt(128)
// h >= 32: K head h-32 (cols 4096+(h-32)*128), out Kr + (h-32)*S*HD, scale = 1
__global__ void rope_kernel(const bf16_t* __restrict__ qkv, bf16_t* __restrict__ Qr,
                            bf16_t* __restrict__ Kr, const int* __restrict__ pos) {
    int idx = blockIdx.x * blockDim.x + threadIdx.x;
    int total = S_LEN * 40 * 64;
    if (idx >= total) return;
    int d = idx & 63;
    int h = (idx >> 6) % 40;
    int s = idx / (64 * 40);
    int colbase = (h < 32) ? h * 128 : 4096 + (h - 32) * 128;
    bf16_t* ob = (h < 32) ? Qr + ((size_t)h * S_LEN + s) * HD
                          : Kr + ((size_t)(h - 32) * S_LEN + s) * HD;
    float scale = (h < 32) ? 0.1275174310f : 1.0f;
    const bf16_t* base = qkv + (size_t)s * NQKV + colbase;
    float x0 = (float)base[d], x1 = (float)base[d + 64];
    float p = (float)pos[s];
    float invf = fast_exp2(-0.20762050593046935f * (float)d);  // log2(10000)/64
    float f = p * invf;
    float sn, cs;
    __sincosf(f, &sn, &cs);
    float o0 = (x0 * cs - x1 * sn) * scale;
    float o1 = (x1 * cs + x0 * sn) * scale;
    ob[d] = (bf16_t)o0;
    ob[d + 64] = (bf16_t)o1;
}

// ---------------- flash attention v5 (unchanged from round 15) ----------------
#define PLD 68
__global__ __launch_bounds__(512) void attn_kernel(const bf16_t* __restrict__ Q,
                                                   const bf16_t* __restrict__ K,
                                                   const bf16_t* __restrict__ Vt,
                                                   bf16_t* __restrict__ O) {
    __shared__ bf16_t Ks[4][64 * 128];   // [kv row][d], swizzled chunks
    __shared__ bf16_t Vs[4][128 * 64];   // [d][kv], swizzled chunks
    __shared__ bf16_t Pl[8][16 * PLD];
    const int tid = threadIdx.x;
    const int lane = tid & 63, w = tid >> 6;   // w: 0..7
    const int bid = blockIdx.x;
    const int h = bid & 31;
    const int x = bid >> 5;              // 0..7
    const int grp = w >> 2, wi = w & 3;
    const int kv = h >> 2;               // N_REP = 4
    const int quad = lane >> 4, c16 = lane & 15;
    const int c7 = c16 & 7;
    const bf16_t* Qh = Q + (size_t)h * S_LEN * HD;
    const bf16_t* Kh = K + (size_t)kv * S_LEN * HD;
    const bf16_t* Vh = Vt + (size_t)kv * HD * S_LEN;
    bf16_t* P = Pl[w];

    auto stage = [&](int slot, int kb) {
        bf16_t* Kd = Ks[slot];
        bf16_t* Vd = Vs[slot];
#pragma unroll
        for (int j = 0; j < 2; ++j) {
            int i = w * 2 + j;           // 16 instrs across 8 waves
            {   // K: instr covers 4 rows of 256B
                int row = 4 * i + (lane >> 4);
                int sc = (lane & 15) ^ (row & 7);
                gload_lds16(Kh + (size_t)(kb + row) * HD + sc * 8, Kd + i * 512);
            }
            {   // V: instr covers 8 rows of 128B
                int row = 8 * i + (lane >> 3);
                int sc = (lane & 7) ^ ((lane >> 3) & 7);
                gload_lds16(Vh + (size_t)row * S_LEN + kb + sc * 8, Vd + i * 512);
            }
        }
    };

    bf16x8 ones;
#pragma unroll
    for (int j = 0; j < 8; ++j) ones[j] = (bf16_t)1.0f;

    for (int ph = 0; ph < 2; ++ph) {
        const int qt = (ph == 0) ? x : 15 - x;
        const int R = qt + 1;            // rounds for this q-tile
        const int qb = qt * 128 + wi * 32;

        bf16x8 qf[2][4];
#pragma unroll
        for (int rg = 0; rg < 2; ++rg)
#pragma unroll
            for (int c = 0; c < 4; ++c)
                qf[rg][c] = *(const bf16x8*)(Qh + (size_t)(qb + rg * 16 + c16) * HD + c * 32 + quad * 8);

        f32x4 acc_o[2][8];
#pragma unroll
        for (int rg = 0; rg < 2; ++rg)
#pragma unroll
            for (int dt = 0; dt < 8; ++dt) acc_o[rg][dt] = (f32x4){0.f, 0.f, 0.f, 0.f};
        f32x4 acc_l[2] = {(f32x4){0.f, 0.f, 0.f, 0.f}, (f32x4){0.f, 0.f, 0.f, 0.f}};
        float m[2][4];
#pragma unroll
        for (int rg = 0; rg < 2; ++rg)
#pragma unroll
            for (int r = 0; r < 4; ++r) m[rg][r] = -1e30f;

        stage(0, 0);
        stage(1, 64);
        __syncthreads();

        for (int r = 0; r < R; ++r) {
            int jn0 = 2 * r + 2, jn1 = 2 * r + 3;
            if (jn0 < 2 * R) stage(jn0 & 3, jn0 * 64);
            if (jn1 < 2 * R) stage(jn1 & 3, jn1 * 64);

            const int j = 2 * r + grp;   // this group's kv tile
            const int kb = j * 64;
            const bf16_t* Kb = Ks[j & 3];
            const bf16_t* Vb = Vs[j & 3];

            if (kb <= qb + 31) {         // wave-active
                const bool diag = (kb + 63 > qb);

                f32x4 sacc[2][4];
#pragma unroll
                for (int rg = 0; rg < 2; ++rg)
#pragma unroll
                    for (int t = 0; t < 4; ++t) sacc[rg][t] = (f32x4){0.f, 0.f, 0.f, 0.f};
#pragma unroll
                for (int t = 0; t < 4; ++t) {
                    const bf16_t* krow = Kb + (t * 16 + c16) * 128;
#pragma unroll
                    for (int cc = 0; cc < 4; ++cc) {
                        bf16x8 kf = *(const bf16x8*)(krow + (((cc * 4 + quad) ^ c7) * 8));
                        sacc[0][t] = __builtin_amdgcn_mfma_f32_16x16x32_bf16(qf[0][cc], kf, sacc[0][t], 0, 0, 0);
                        sacc[1][t] = __builtin_amdgcn_mfma_f32_16x16x32_bf16(qf[1][cc], kf, sacc[1][t], 0, 0, 0);
                    }
                }
                bf16x8 pf[2][2];
#pragma unroll
                for (int rg = 0; rg < 2; ++rg) {
                    float p[4][4], mxr[4];
#pragma unroll
                    for (int r4 = 0; r4 < 4; ++r4) {
                        int qq = qb + rg * 16 + quad * 4 + r4;
#pragma unroll
                        for (int t = 0; t < 4; ++t) {
                            float sv = sacc[rg][t][r4];
                            if (diag && (kb + t * 16 + c16 > qq)) sv = -1e30f;
                            p[t][r4] = sv;
                        }
                        float mx = fmaxf(fmaxf(p[0][r4], p[1][r4]), fmaxf(p[2][r4], p[3][r4]));
                        mx = fmaxf(mx, __shfl_xor(mx, 1));
                        mx = fmaxf(mx, __shfl_xor(mx, 2));
                        mx = fmaxf(mx, __shfl_xor(mx, 4));
                        mx = fmaxf(mx, __shfl_xor(mx, 8));
                        mxr[r4] = mx;
                    }
                    bool resc = false;
#pragma unroll
                    for (int r4 = 0; r4 < 4; ++r4) resc = resc || (mxr[r4] > m[rg][r4] + 8.f);
                    if (__any(resc)) {
#pragma unroll
                        for (int r4 = 0; r4 < 4; ++r4) {
                            float mn = fmaxf(m[rg][r4], mxr[r4]);
                            float al = fast_exp2(m[rg][r4] - mn);
                            m[rg][r4] = mn;
                            acc_l[rg][r4] *= al;
#pragma unroll
                            for (int dt = 0; dt < 8; ++dt) acc_o[rg][dt][r4] *= al;
                        }
                    }
#pragma unroll
                    for (int r4 = 0; r4 < 4; ++r4)
#pragma unroll
                        for (int t = 0; t < 4; ++t)
                            p[t][r4] = fast_exp2(p[t][r4] - m[rg][r4]);
#pragma unroll
                    for (int t = 0; t < 4; ++t)
#pragma unroll
                        for (int r4 = 0; r4 < 4; ++r4)
                            P[(quad * 4 + r4) * PLD + t * 16 + c16] = (bf16_t)p[t][r4];
                    pf[rg][0] = *(const bf16x8*)(P + c16 * PLD + quad * 8);
                    pf[rg][1] = *(const bf16x8*)(P + c16 * PLD + 32 + quad * 8);
                }
                acc_l[0] = __builtin_amdgcn_mfma_f32_16x16x32_bf16(pf[0][0], ones, acc_l[0], 0, 0, 0);
                acc_l[0] = __builtin_amdgcn_mfma_f32_16x16x32_bf16(pf[0][1], ones, acc_l[0], 0, 0, 0);
                acc_l[1] = __builtin_amdgcn_mfma_f32_16x16x32_bf16(pf[1][0], ones, acc_l[1], 0, 0, 0);
                acc_l[1] = __builtin_amdgcn_mfma_f32_16x16x32_bf16(pf[1][1], ones, acc_l[1], 0, 0, 0);
#pragma unroll
                for (int dt = 0; dt < 8; ++dt) {
                    const bf16_t* vrow = Vb + (dt * 16 + c16) * 64;
                    bf16x8 vf0 = *(const bf16x8*)(vrow + ((quad ^ c7) * 8));
                    bf16x8 vf1 = *(const bf16x8*)(vrow + (((4 + quad) ^ c7) * 8));
                    acc_o[0][dt] = __builtin_amdgcn_mfma_f32_16x16x32_bf16(pf[0][0], vf0, acc_o[0][dt], 0, 0, 0);
                    acc_o[0][dt] = __builtin_amdgcn_mfma_f32_16x16x32_bf16(pf[0][1], vf1, acc_o[0][dt], 0, 0, 0);
                    acc_o[1][dt] = __builtin_amdgcn_mfma_f32_16x16x32_bf16(pf[1][0], vf0, acc_o[1][dt], 0, 0, 0);
                    acc_o[1][dt] = __builtin_amdgcn_mfma_f32_16x16x32_bf16(pf[1][1], vf1, acc_o[1][dt], 0, 0, 0);
                }
            }
            __syncthreads();
        }

        // ---- merge the two kv-split groups (grp1 -> LDS, grp0 combines & writes O) ----
        float* s0 = (float*)&Ks[0][0];   // 48 idx x 256 x 4B = 49KB <= 64KB
        float* s1 = (float*)&Vs[0][0];   // 32 idx x 256 x 4B = 32KB <= 64KB
        const int sl = wi * 64 + lane;
        if (grp == 1) {
#pragma unroll
            for (int rg = 0; rg < 2; ++rg)
#pragma unroll
                for (int r4 = 0; r4 < 4; ++r4) {
                    s0[(rg * 4 + r4) * 256 + sl] = m[rg][r4];
                    s0[(8 + rg * 4 + r4) * 256 + sl] = acc_l[rg][r4];
                }
#pragma unroll
            for (int dt = 0; dt < 8; ++dt)
#pragma unroll
                for (int r4 = 0; r4 < 4; ++r4) {
                    s0[(16 + dt * 4 + r4) * 256 + sl] = acc_o[0][dt][r4];
                    s1[(dt * 4 + r4) * 256 + sl] = acc_o[1][dt][r4];
                }
        }
        __syncthreads();
        if (grp == 0) {
#pragma unroll
            for (int rg = 0; rg < 2; ++rg)
#pragma unroll
                for (int r4 = 0; r4 < 4; ++r4) {
                    float m1 = s0[(rg * 4 + r4) * 256 + sl];
                    float l1 = s0[(8 + rg * 4 + r4) * 256 + sl];
                    float mm = fmaxf(m[rg][r4], m1);
                    float a0 = fast_exp2(m[rg][r4] - mm);
                    float a1 = fast_exp2(m1 - mm);
                    float ll = acc_l[rg][r4] * a0 + l1 * a1;
                    float inv = 1.f / ll;
                    bf16_t* orow = &O[(size_t)(qb + rg * 16 + quad * 4 + r4) * HIDDEN + h * HD];
#pragma unroll
                    for (int dt = 0; dt < 8; ++dt) {
                        float o1 = (rg == 0) ? s0[(16 + dt * 4 + r4) * 256 + sl]
                                             : s1[(dt * 4 + r4) * 256 + sl];
                        float val = (acc_o[rg][dt][r4] * a0 + o1 * a1) * inv;
                        orow[dt * 16 + c16] = (bf16_t)val;
                    }
                }
        }
        __syncthreads();                 // scratch free before next q-tile's staging
    }
}

// ---------------- host ----------------
extern "C" void kernel_launch(void* const* d_in, const int* in_sizes, int n_in,
                              void* d_out, int out_size, void* d_ws, size_t ws_size,
                              hipStream_t stream) {
    const float* hs = (const float*)d_in[0];
    const float* Wq = (const float*)d_in[1];
    const float* Wk = (const float*)d_in[2];
    const float* Wv = (const float*)d_in[3];
    const float* Wo = (const float*)d_in[4];
    const int* pos = (const int*)d_in[6];
    float* out = (float*)d_out;

    char* ws = (char*)d_ws;
    size_t off = 0;
    auto alloc = [&](size_t bytes) -> void* {
        void* p = ws + off;
        off += (bytes + 255) & ~(size_t)255;
        return p;
    };
    bf16_t* hB    = (bf16_t*)alloc((size_t)S_LEN * HIDDEN * 2);
    bf16_t* WqkvT = (bf16_t*)alloc((size_t)NQKV * HIDDEN * 2);   // [6144][4096]
    bf16_t* WoT   = (bf16_t*)alloc((size_t)HIDDEN * HIDDEN * 2);
    bf16_t* QKV   = (bf16_t*)alloc((size_t)S_LEN * NQKV * 2);    // [2048][6144] bf16
    bf16_t* Qr    = (bf16_t*)alloc((size_t)NH * S_LEN * HD * 2);
    bf16_t* Kr    = (bf16_t*)alloc((size_t)NKV * S_LEN * HD * 2);
    bf16_t* Vt    = (bf16_t*)alloc((size_t)NKV * HD * S_LEN * 2);
    bf16_t* Oat   = (bf16_t*)alloc((size_t)S_LEN * HIDDEN * 2);

    // 1. cast hidden to bf16
    cast_bf16_kernel<<<2048, 256, 0, stream>>>(hs, hB, S_LEN * HIDDEN / 4);
    // 2. fused weight prep: all 4 transpose-casts in one launch (10240 blocks)
    weight_prep_kernel<<<10240, 256, 0, stream>>>(Wq, Wk, Wv, Wo, WqkvT, WoT);
    // 3. fused QKV projection -> bf16 [2048][6144]; 256x192 tile -> 256 blocks = 1/CU
    gemm_ring2_kernel<192, bf16_t><<<(S_LEN / 256) * (NQKV / 192), 512, 0, stream>>>(hB, WqkvT, QKV, S_LEN, NQKV, HIDDEN);
    // 4. fused RoPE (Q + K in one launch; Q scale folds log2e/sqrt(128))
    rope_kernel<<<(S_LEN * 40 * 64 + 255) / 256, 256, 0, stream>>>(QKV, Qr, Kr, pos);
    // 5. V transpose: bf16 [S][1024] (stride 6144) -> [1024][2048] == [NKV][128][S]
    transpose_bf16_kernel<<<dim3(1024 / 64, S_LEN / 64), 256, 0, stream>>>(QKV + 5120, Vt, NQKV, S_LEN);
    // 6. flash attention v5: 256 blocks, 1/CU, 17 uniform rounds
    attn_kernel<<<256, 512, 0, stream>>>(Qr, Kr, Vt, Oat);
    // 7. output projection (fp32 out); 256x128 tile -> 256 blocks = 1/CU
    gemm_ring2_kernel<128, float><<<(S_LEN / 256) * (HIDDEN / 128), 512, 0, stream>>>(Oat, WoT, out, S_LEN, HIDDEN, HIDDEN);
}

// Round 19
// 316.059 us; speedup vs baseline: 1.0771x; 1.0166x over previous
//
#include <hip/hip_runtime.h>
#include <hip/hip_bf16.h>

#define S_LEN 2048
#define HIDDEN 4096
#define NH 32
#define NKV 8
#define HD 128
#define NQKV 6144   // NH*HD + 2*NKV*HD

typedef __bf16 bf16_t;
typedef __bf16 bf16x8 __attribute__((ext_vector_type(8)));
typedef __bf16 bf16x4 __attribute__((ext_vector_type(4)));
typedef float f32x4 __attribute__((ext_vector_type(4)));

typedef __attribute__((address_space(1))) void gvoid;
typedef __attribute__((address_space(3))) void lvoid;

__device__ __forceinline__ void gload_lds16(const void* g, void* l) {
    __builtin_amdgcn_global_load_lds((gvoid*)g, (lvoid*)l, 16, 0, 0);
}

__device__ __forceinline__ float fast_exp2(float x) {
    return __builtin_amdgcn_exp2f(x);   // v_exp_f32 (2^x native)
}

__device__ __forceinline__ unsigned int pack2_bf16(float lo, float hi) {
    bf16_t l = (bf16_t)lo, h = (bf16_t)hi;
    unsigned short lu, hu;
    __builtin_memcpy(&lu, &l, 2);
    __builtin_memcpy(&hu, &h, 2);
    return ((unsigned int)hu << 16) | (unsigned int)lu;
}

// ---------------- fused prep: 4 weight transpose-casts + hidden cast, ONE launch ----------------
// b < 4096   : Wq 64x64 tile -> WqkvT rows 0..4095
// b < 5120   : Wk tile       -> WqkvT rows 4096..5119
// b < 6144   : Wv tile       -> WqkvT rows 5120..6143
// b < 10240  : Wo tile       -> WoT
// b < 12288  : hidden cast fp32->bf16, 1024 float4 per block
__global__ __launch_bounds__(256) void prep_kernel(const float* __restrict__ hs,
                                                   const float* __restrict__ Wq,
                                                   const float* __restrict__ Wk,
                                                   const float* __restrict__ Wv,
                                                   const float* __restrict__ Wo,
                                                   bf16_t* __restrict__ hB,
                                                   bf16_t* __restrict__ WqkvT,
                                                   bf16_t* __restrict__ WoT) {
    __shared__ unsigned int t2[64][34];
    int b = blockIdx.x;
    const int t = threadIdx.x;
    if (b >= 10240) {   // hidden cast: 2048 blocks x 1024 float4
        int base = (b - 10240) * 1024 + t;
#pragma unroll
        for (int i = 0; i < 4; ++i) {
            int idx = base + i * 256;
            float4 v = ((const float4*)hs)[idx];
            bf16x4 o;
            o.x = (bf16_t)v.x; o.y = (bf16_t)v.y; o.z = (bf16_t)v.z; o.w = (bf16_t)v.w;
            ((bf16x4*)hB)[idx] = o;
        }
        return;
    }
    const float* in;
    bf16_t* out;
    int ldin, ldout, cx, ry;
    if (b < 4096) {
        in = Wq; out = WqkvT; ldin = HIDDEN; ldout = HIDDEN;
        cx = b & 63; ry = b >> 6;
    } else if (b < 5120) {
        b -= 4096;
        in = Wk; out = WqkvT + (size_t)4096 * HIDDEN; ldin = 1024; ldout = HIDDEN;
        cx = b & 15; ry = b >> 4;
    } else if (b < 6144) {
        b -= 5120;
        in = Wv; out = WqkvT + (size_t)5120 * HIDDEN; ldin = 1024; ldout = HIDDEN;
        cx = b & 15; ry = b >> 4;
    } else {
        b -= 6144;
        in = Wo; out = WoT; ldin = HIDDEN; ldout = HIDDEN;
        cx = b & 63; ry = b >> 6;
    }
    const int c0 = cx * 64, r0 = ry * 64;
    const int tx4 = t & 15, tp = t >> 4;
#pragma unroll
    for (int i = 0; i < 2; ++i) {
        int rp = tp + i * 16;
        const float* p0 = &in[(size_t)(r0 + 2 * rp) * ldin + c0 + tx4 * 4];
        float4 a = *(const float4*)p0;
        float4 bb = *(const float4*)(p0 + ldin);
        t2[tx4 * 4 + 0][rp] = pack2_bf16(a.x, bb.x);
        t2[tx4 * 4 + 1][rp] = pack2_bf16(a.y, bb.y);
        t2[tx4 * 4 + 2][rp] = pack2_bf16(a.z, bb.z);
        t2[tx4 * 4 + 3][rp] = pack2_bf16(a.w, bb.w);
    }
    __syncthreads();
    const int q = t & 3, cc = t >> 2;
    uint2 v0 = *(const uint2*)&t2[cc][q * 8 + 0];
    uint2 v1 = *(const uint2*)&t2[cc][q * 8 + 2];
    uint2 v2 = *(const uint2*)&t2[cc][q * 8 + 4];
    uint2 v3 = *(const uint2*)&t2[cc][q * 8 + 6];
    bf16_t* o = &out[(size_t)(c0 + cc) * ldout + r0 + q * 16];
    *(uint4*)o = make_uint4(v0.x, v0.y, v1.x, v1.y);
    *(uint4*)(o + 8) = make_uint4(v2.x, v2.y, v3.x, v3.y);
}

// ---------------- ring-3 counted-vmcnt GEMM: BM=256, per-wave 64x(BN/2) (round-16 best) ----------------
template<int BN, typename OutT>
__global__ __launch_bounds__(512, 2) void gemm_ring2_kernel(const bf16_t* __restrict__ A,
                                                            const bf16_t* __restrict__ Bt,
                                                            OutT* __restrict__ C,
                                                            int M, int N, int K) {
    constexpr int NF = BN / 32;          // per-wave col frags (6 for 192, 4 for 128)
    __shared__ bf16_t As[3][256 * 32];
    __shared__ bf16_t Bs[3][BN * 32];
    const int tid = threadIdx.x;
    const int lane = tid & 63, w = tid >> 6;
    const int wm = w >> 1, wn = w & 1;
    const int g = lane >> 4, c16 = lane & 15;
    const int srow = lane >> 2;                              // row within a 16-row DMA instr
    const int scg = ((lane & 3) ^ ((lane >> 3) & 3)) * 8;    // pre-swizzled global chunk (elems)
    const int rdc = (g ^ ((c16 >> 1) & 3)) * 8;              // swizzled read chunk (elems)

    // XCD swizzle, bm-fastest
    const int nbm = M / 256;
    const int cpx = gridDim.x >> 3;
    const int bid = blockIdx.x;
    const int swz = (bid & 7) * cpx + (bid >> 3);
    const int bm = swz % nbm, bn = swz / nbm;

    const bf16_t* Ab = A + (size_t)(bm * 256) * K;
    const bf16_t* Bb = Bt + (size_t)bn * BN * K;

    auto stage = [&](int slot, int kt) {
        const bf16_t* Ak = Ab + (size_t)kt * 32;
        const bf16_t* Bk = Bb + (size_t)kt * 32;
#pragma unroll
        for (int j = 0; j < 2; ++j) {    // A: 16 instrs, 2/wave (rows 32w..32w+31)
            int rb = 32 * w + 16 * j;
            gload_lds16(Ak + (size_t)(rb + srow) * K + scg, &As[slot][rb * 32]);
        }
        if constexpr (BN == 192) {       // B: 12 instrs: waves 0-3 x2, waves 4-7 x1
            if (w < 4) {
#pragma unroll
                for (int j = 0; j < 2; ++j) {
                    int rb = 32 * w + 16 * j;
                    gload_lds16(Bk + (size_t)(rb + srow) * K + scg, &Bs[slot][rb * 32]);
                }
            } else {
                int rb = 128 + 16 * (w - 4);
                gload_lds16(Bk + (size_t)(rb + srow) * K + scg, &Bs[slot][rb * 32]);
            }
        } else {                         // BN==128: B 8 instrs, 1/wave
            int rb = 16 * w;
            gload_lds16(Bk + (size_t)(rb + srow) * K + scg, &Bs[slot][rb * 32]);
        }
    };

    f32x4 acc[4][NF];
#pragma unroll
    for (int i = 0; i < 4; ++i)
#pragma unroll
        for (int j = 0; j < NF; ++j)
            acc[i][j] = (f32x4){0.f, 0.f, 0.f, 0.f};

    const int NT = K / 32;
    stage(0, 0);
    stage(1, 1);

    int slot = 0, slot2 = 2;             // slot = t%3, slot2 = (t+2)%3
    for (int t = 0; t < NT; ++t) {
        asm volatile("s_waitcnt vmcnt(3)" ::: "memory");
        __builtin_amdgcn_s_barrier();
        __builtin_amdgcn_sched_barrier(0);
        __builtin_amdgcn_s_setprio(1);

        bf16x8 af[4], bf[NF];
#pragma unroll
        for (int i = 0; i < 4; ++i) {
            int arow = wm * 64 + i * 16 + c16;
            af[i] = *(const bf16x8*)&As[slot][arow * 32 + rdc];
        }
#pragma unroll
        for (int j = 0; j < NF; ++j) {
            int brow = wn * (BN / 2) + j * 16 + c16;
            bf[j] = *(const bf16x8*)&Bs[slot][brow * 32 + rdc];
        }
        int nk = t + 2;
        if (nk >= NT) nk -= NT;          // wrap-stage: keeps ledger uniform, never read
        stage(slot2, nk);

        // NO lgkmcnt(0) fence: compiler interleaves ds_reads with MFMAs (counted lgkmcnt)
#pragma unroll
        for (int i = 0; i < 4; ++i)
#pragma unroll
            for (int j = 0; j < NF; ++j)
                acc[i][j] = __builtin_amdgcn_mfma_f32_16x16x32_bf16(af[i], bf[j], acc[i][j], 0, 0, 0);
        __builtin_amdgcn_s_setprio(0);

        slot = (slot + 1) % 3;
        slot2 = (slot2 + 1) % 3;
    }

#pragma unroll
    for (int mi = 0; mi < 4; ++mi)
#pragma unroll
        for (int ni = 0; ni < NF; ++ni) {
            int col = bn * BN + wn * (BN / 2) + ni * 16 + c16;
#pragma unroll
            for (int r = 0; r < 4; ++r) {
                int row = bm * 256 + wm * 64 + mi * 16 + g * 4 + r;
                C[(size_t)row * N + col] = (OutT)acc[mi][ni][r];
            }
        }
}

// ---------------- fused RoPE + V-transpose, ONE launch ----------------
// b < 512: V-transpose 64x64 tile (QKV cols 5120.., stride NQKV -> Vt stride S_LEN)
// b >= 512: RoPE for Q (h<32) and K (h>=32)
__global__ __launch_bounds__(256) void rope_vt_kernel(const bf16_t* __restrict__ qkv,
                                                      bf16_t* __restrict__ Qr,
                                                      bf16_t* __restrict__ Kr,
                                                      bf16_t* __restrict__ Vt,
                                                      const int* __restrict__ pos) {
    const int t = threadIdx.x;
    int b = blockIdx.x;
    if (b < 512) {   // V transpose: in [2048 r][1024 c] (stride NQKV) -> out [1024][2048]
        __shared__ unsigned int t2[64][34];
        const int cx = b & 15, ry = b >> 4;
        const int c0 = cx * 64, r0 = ry * 64;
        const bf16_t* in = qkv + 5120;
        const int tx4 = t & 15, tp = t >> 4;
#pragma unroll
        for (int i = 0; i < 2; ++i) {
            int rp = tp + i * 16;
            const bf16_t* p0 = &in[(size_t)(r0 + 2 * rp) * NQKV + c0 + tx4 * 4];
            bf16x4 a = *(const bf16x4*)p0;
            bf16x4 bb = *(const bf16x4*)(p0 + NQKV);
#pragma unroll
            for (int k2 = 0; k2 < 4; ++k2) {
                unsigned short lu, hu;
                bf16_t la = a[k2], hb = bb[k2];
                __builtin_memcpy(&lu, &la, 2);
                __builtin_memcpy(&hu, &hb, 2);
                t2[tx4 * 4 + k2][rp] = ((unsigned int)hu << 16) | (unsigned int)lu;
            }
        }
        __syncthreads();
        const int q = t & 3, cc = t >> 2;
        uint2 v0 = *(const uint2*)&t2[cc][q * 8 + 0];
        uint2 v1 = *(const uint2*)&t2[cc][q * 8 + 2];
        uint2 v2 = *(const uint2*)&t2[cc][q * 8 + 4];
        uint2 v3 = *(const uint2*)&t2[cc][q * 8 + 6];
        bf16_t* o = &Vt[(size_t)(c0 + cc) * S_LEN + r0 + q * 16];
        *(uint4*)o = make_uint4(v0.x, v0.y, v1.x, v1.y);
        *(uint4*)(o + 8) = make_uint4(v2.x, v2.y, v3.x, v3.y);
        return;
    }
    int idx = (b - 512) * 256 + t;
    int total = S_LEN * 40 * 64;
    if (idx >= total) return;
    int d = idx & 63;
    int h = (idx >> 6) % 40;
    int s = idx / (64 * 40);
    int colbase = (h < 32) ? h * 128 : 4096 + (h - 32) * 128;
    bf16_t* ob = (h < 32) ? Qr + ((size_t)h * S_LEN + s) * HD
                          : Kr + ((size_t)(h - 32) * S_LEN + s) * HD;
    float scale = (h < 32) ? 0.1275174310f : 1.0f;
    const bf16_t* base = qkv + (size_t)s * NQKV + colbase;
    float x0 = (float)base[d], x1 = (float)base[d + 64];
    float p = (float)pos[s];
    float invf = fast_exp2(-0.20762050593046935f * (float)d);  // log2(10000)/64
    float f = p * invf;
    float sn, cs;
    __sincosf(f, &sn, &cs);
    float o0 = (x0 * cs - x1 * sn) * scale;
    float o1 = (x1 * cs + x0 * sn) * scale;
    ob[d] = (bf16_t)o0;
    ob[d + 64] = (bf16_t)o1;
}

// ---------------- flash attention v5 (unchanged) ----------------
#define PLD 68
__global__ __launch_bounds__(512) void attn_kernel(const bf16_t* __restrict__ Q,
                                                   const bf16_t* __restrict__ K,
                                                   const bf16_t* __restrict__ Vt,
                                                   bf16_t* __restrict__ O) {
    __shared__ bf16_t Ks[4][64 * 128];   // [kv row][d], swizzled chunks
    __shared__ bf16_t Vs[4][128 * 64];   // [d][kv], swizzled chunks
    __shared__ bf16_t Pl[8][16 * PLD];
    const int tid = threadIdx.x;
    const int lane = tid & 63, w = tid >> 6;   // w: 0..7
    const int bid = blockIdx.x;
    const int h = bid & 31;
    const int x = bid >> 5;              // 0..7
    const int grp = w >> 2, wi = w & 3;
    const int kv = h >> 2;               // N_REP = 4
    const int quad = lane >> 4, c16 = lane & 15;
    const int c7 = c16 & 7;
    const bf16_t* Qh = Q + (size_t)h * S_LEN * HD;
    const bf16_t* Kh = K + (size_t)kv * S_LEN * HD;
    const bf16_t* Vh = Vt + (size_t)kv * HD * S_LEN;
    bf16_t* P = Pl[w];

    auto stage = [&](int slot, int kb) {
        bf16_t* Kd = Ks[slot];
        bf16_t* Vd = Vs[slot];
#pragma unroll
        for (int j = 0; j < 2; ++j) {
            int i = w * 2 + j;           // 16 instrs across 8 waves
            {   // K: instr covers 4 rows of 256B
                int row = 4 * i + (lane >> 4);
                int sc = (lane & 15) ^ (row & 7);
                gload_lds16(Kh + (size_t)(kb + row) * HD + sc * 8, Kd + i * 512);
            }
            {   // V: instr covers 8 rows of 128B
                int row = 8 * i + (lane >> 3);
                int sc = (lane & 7) ^ ((lane >> 3) & 7);
                gload_lds16(Vh + (size_t)row * S_LEN + kb + sc * 8, Vd + i * 512);
            }
        }
    };

    bf16x8 ones;
#pragma unroll
    for (int j = 0; j < 8; ++j) ones[j] = (bf16_t)1.0f;

    for (int ph = 0; ph < 2; ++ph) {
        const int qt = (ph == 0) ? x : 15 - x;
        const int R = qt + 1;            // rounds for this q-tile
        const int qb = qt * 128 + wi * 32;

        bf16x8 qf[2][4];
#pragma unroll
        for (int rg = 0; rg < 2; ++rg)
#pragma unroll
            for (int c = 0; c < 4; ++c)
                qf[rg][c] = *(const bf16x8*)(Qh + (size_t)(qb + rg * 16 + c16) * HD + c * 32 + quad * 8);

        f32x4 acc_o[2][8];
#pragma unroll
        for (int rg = 0; rg < 2; ++rg)
#pragma unroll
            for (int dt = 0; dt < 8; ++dt) acc_o[rg][dt] = (f32x4){0.f, 0.f, 0.f, 0.f};
        f32x4 acc_l[2] = {(f32x4){0.f, 0.f, 0.f, 0.f}, (f32x4){0.f, 0.f, 0.f, 0.f}};
        float m[2][4];
#pragma unroll
        for (int rg = 0; rg < 2; ++rg)
#pragma unroll
            for (int r = 0; r < 4; ++r) m[rg][r] = -1e30f;

        stage(0, 0);
        stage(1, 64);
        __syncthreads();

        for (int r = 0; r < R; ++r) {
            int jn0 = 2 * r + 2, jn1 = 2 * r + 3;
            if (jn0 < 2 * R) stage(jn0 & 3, jn0 * 64);
            if (jn1 < 2 * R) stage(jn1 & 3, jn1 * 64);

            const int j = 2 * r + grp;   // this group's kv tile
            const int kb = j * 64;
            const bf16_t* Kb = Ks[j & 3];
            const bf16_t* Vb = Vs[j & 3];

            if (kb <= qb + 31) {         // wave-active
                const bool diag = (kb + 63 > qb);

                f32x4 sacc[2][4];
#pragma unroll
                for (int rg = 0; rg < 2; ++rg)
#pragma unroll
                    for (int t = 0; t < 4; ++t) sacc[rg][t] = (f32x4){0.f, 0.f, 0.f, 0.f};
#pragma unroll
                for (int t = 0; t < 4; ++t) {
                    const bf16_t* krow = Kb + (t * 16 + c16) * 128;
#pragma unroll
                    for (int cc = 0; cc < 4; ++cc) {
                        bf16x8 kf = *(const bf16x8*)(krow + (((cc * 4 + quad) ^ c7) * 8));
                        sacc[0][t] = __builtin_amdgcn_mfma_f32_16x16x32_bf16(qf[0][cc], kf, sacc[0][t], 0, 0, 0);
                        sacc[1][t] = __builtin_amdgcn_mfma_f32_16x16x32_bf16(qf[1][cc], kf, sacc[1][t], 0, 0, 0);
                    }
                }
                bf16x8 pf[2][2];
#pragma unroll
                for (int rg = 0; rg < 2; ++rg) {
                    float p[4][4], mxr[4];
#pragma unroll
                    for (int r4 = 0; r4 < 4; ++r4) {
                        int qq = qb + rg * 16 + quad * 4 + r4;
#pragma unroll
                        for (int t = 0; t < 4; ++t) {
                            float sv = sacc[rg][t][r4];
                            if (diag && (kb + t * 16 + c16 > qq)) sv = -1e30f;
                            p[t][r4] = sv;
                        }
                        float mx = fmaxf(fmaxf(p[0][r4], p[1][r4]), fmaxf(p[2][r4], p[3][r4]));
                        mx = fmaxf(mx, __shfl_xor(mx, 1));
                        mx = fmaxf(mx, __shfl_xor(mx, 2));
                        mx = fmaxf(mx, __shfl_xor(mx, 4));
                        mx = fmaxf(mx, __shfl_xor(mx, 8));
                        mxr[r4] = mx;
                    }
                    bool resc = false;
#pragma unroll
                    for (int r4 = 0; r4 < 4; ++r4) resc = resc || (mxr[r4] > m[rg][r4] + 8.f);
                    if (__any(resc)) {
#pragma unroll
                        for (int r4 = 0; r4 < 4; ++r4) {
                            float mn = fmaxf(m[rg][r4], mxr[r4]);
                            float al = fast_exp2(m[rg][r4] - mn);
                            m[rg][r4] = mn;
                            acc_l[rg][r4] *= al;
#pragma unroll
                            for (int dt = 0; dt < 8; ++dt) acc_o[rg][dt][r4] *= al;
                        }
                    }
#pragma unroll
                    for (int r4 = 0; r4 < 4; ++r4)
#pragma unroll
                        for (int t = 0; t < 4; ++t)
                            p[t][r4] = fast_exp2(p[t][r4] - m[rg][r4]);
#pragma unroll
                    for (int t = 0; t < 4; ++t)
#pragma unroll
                        for (int r4 = 0; r4 < 4; ++r4)
                            P[(quad * 4 + r4) * PLD + t * 16 + c16] = (bf16_t)p[t][r4];
                    pf[rg][0] = *(const bf16x8*)(P + c16 * PLD + quad * 8);
                    pf[rg][1] = *(const bf16x8*)(P + c16 * PLD + 32 + quad * 8);
                }
                acc_l[0] = __builtin_amdgcn_mfma_f32_16x16x32_bf16(pf[0][0], ones, acc_l[0], 0, 0, 0);
                acc_l[0] = __builtin_amdgcn_mfma_f32_16x16x32_bf16(pf[0][1], ones, acc_l[0], 0, 0, 0);
                acc_l[1] = __builtin_amdgcn_mfma_f32_16x16x32_bf16(pf[1][0], ones, acc_l[1], 0, 0, 0);
                acc_l[1] = __builtin_amdgcn_mfma_f32_16x16x32_bf16(pf[1][1], ones, acc_l[1], 0, 0, 0);
#pragma unroll
                for (int dt = 0; dt < 8; ++dt) {
                    const bf16_t* vrow = Vb + (dt * 16 + c16) * 64;
                    bf16x8 vf0 = *(const bf16x8*)(vrow + ((quad ^ c7) * 8));
                    bf16x8 vf1 = *(const bf16x8*)(vrow + (((4 + quad) ^ c7) * 8));
                    acc_o[0][dt] = __builtin_amdgcn_mfma_f32_16x16x32_bf16(pf[0][0], vf0, acc_o[0][dt], 0, 0, 0);
                    acc_o[0][dt] = __builtin_amdgcn_mfma_f32_16x16x32_bf16(pf[0][1], vf1, acc_o[0][dt], 0, 0, 0);
                    acc_o[1][dt] = __builtin_amdgcn_mfma_f32_16x16x32_bf16(pf[1][0], vf0, acc_o[1][dt], 0, 0, 0);
                    acc_o[1][dt] = __builtin_amdgcn_mfma_f32_16x16x32_bf16(pf[1][1], vf1, acc_o[1][dt], 0, 0, 0);
                }
            }
            __syncthreads();
        }

        // ---- merge the two kv-split groups (grp1 -> LDS, grp0 combines & writes O) ----
        float* s0 = (float*)&Ks[0][0];   // 48 idx x 256 x 4B = 49KB <= 64KB
        float* s1 = (float*)&Vs[0][0];   // 32 idx x 256 x 4B = 32KB <= 64KB
        const int sl = wi * 64 + lane;
        if (grp == 1) {
#pragma unroll
            for (int rg = 0; rg < 2; ++rg)
#pragma unroll
                for (int r4 = 0; r4 < 4; ++r4) {
                    s0[(rg * 4 + r4) * 256 + sl] = m[rg][r4];
                    s0[(8 + rg * 4 + r4) * 256 + sl] = acc_l[rg][r4];
                }
#pragma unroll
            for (int dt = 0; dt < 8; ++dt)
#pragma unroll
                for (int r4 = 0; r4 < 4; ++r4) {
                    s0[(16 + dt * 4 + r4) * 256 + sl] = acc_o[0][dt][r4];
                    s1[(dt * 4 + r4) * 256 + sl] = acc_o[1][dt][r4];
                }
        }
        __syncthreads();
        if (grp == 0) {
#pragma unroll
            for (int rg = 0; rg < 2; ++rg)
#pragma unroll
                for (int r4 = 0; r4 < 4; ++r4) {
                    float m1 = s0[(rg * 4 + r4) * 256 + sl];
                    float l1 = s0[(8 + rg * 4 + r4) * 256 + sl];
                    float mm = fmaxf(m[rg][r4], m1);
                    float a0 = fast_exp2(m[rg][r4] - mm);
                    float a1 = fast_exp2(m1 - mm);
                    float ll = acc_l[rg][r4] * a0 + l1 * a1;
                    float inv = 1.f / ll;
                    bf16_t* orow = &O[(size_t)(qb + rg * 16 + quad * 4 + r4) * HIDDEN + h * HD];
#pragma unroll
                    for (int dt = 0; dt < 8; ++dt) {
                        float o1 = (rg == 0) ? s0[(16 + dt * 4 + r4) * 256 + sl]
                                             : s1[(dt * 4 + r4) * 256 + sl];
                        float val = (acc_o[rg][dt][r4] * a0 + o1 * a1) * inv;
                        orow[dt * 16 + c16] = (bf16_t)val;
                    }
                }
        }
        __syncthreads();                 // scratch free before next q-tile's staging
    }
}

// ---------------- host ----------------
extern "C" void kernel_launch(void* const* d_in, const int* in_sizes, int n_in,
                              void* d_out, int out_size, void* d_ws, size_t ws_size,
                              hipStream_t stream) {
    const float* hs = (const float*)d_in[0];
    const float* Wq = (const float*)d_in[1];
    const float* Wk = (const float*)d_in[2];
    const float* Wv = (const float*)d_in[3];
    const float* Wo = (const float*)d_in[4];
    const int* pos = (const int*)d_in[6];
    float* out = (float*)d_out;

    char* ws = (char*)d_ws;
    size_t off = 0;
    auto alloc = [&](size_t bytes) -> void* {
        void* p = ws + off;
        off += (bytes + 255) & ~(size_t)255;
        return p;
    };
    bf16_t* hB    = (bf16_t*)alloc((size_t)S_LEN * HIDDEN * 2);
    bf16_t* WqkvT = (bf16_t*)alloc((size_t)NQKV * HIDDEN * 2);   // [6144][4096]
    bf16_t* WoT   = (bf16_t*)alloc((size_t)HIDDEN * HIDDEN * 2);
    bf16_t* QKV   = (bf16_t*)alloc((size_t)S_LEN * NQKV * 2);    // [2048][6144] bf16
    bf16_t* Qr    = (bf16_t*)alloc((size_t)NH * S_LEN * HD * 2);
    bf16_t* Kr    = (bf16_t*)alloc((size_t)NKV * S_LEN * HD * 2);
    bf16_t* Vt    = (bf16_t*)alloc((size_t)NKV * HD * S_LEN * 2);
    bf16_t* Oat   = (bf16_t*)alloc((size_t)S_LEN * HIDDEN * 2);

    // 1. fused prep: 4 weight transpose-casts + hidden cast (12288 blocks)
    prep_kernel<<<12288, 256, 0, stream>>>(hs, Wq, Wk, Wv, Wo, hB, WqkvT, WoT);
    // 2. fused QKV projection -> bf16 [2048][6144]; 256x192 tile -> 256 blocks = 1/CU
    gemm_ring2_kernel<192, bf16_t><<<(S_LEN / 256) * (NQKV / 192), 512, 0, stream>>>(hB, WqkvT, QKV, S_LEN, NQKV, HIDDEN);
    // 3. fused RoPE + V-transpose (512 transpose blocks + 20480 rope blocks)
    rope_vt_kernel<<<512 + (S_LEN * 40 * 64 + 255) / 256, 256, 0, stream>>>(QKV, Qr, Kr, Vt, pos);
    // 4. flash attention v5: 256 blocks, 1/CU, 17 uniform rounds
    attn_kernel<<<256, 512, 0, stream>>>(Qr, Kr, Vt, Oat);
    // 5. output projection (fp32 out); 256x128 tile -> 256 blocks = 1/CU
    gemm_ring2_kernel<128, float><<<(S_LEN / 256) * (HIDDEN / 128), 512, 0, stream>>>(Oat, WoT, out, S_LEN, HIDDEN, HIDDEN);
}